// Round 1
// baseline (253.768 us; speedup 1.0000x reference)
//
#include <hip/hip_runtime.h>

#define N_COL 256
#define N_ROW 256
#define N_NEUR (N_COL * N_ROW)      // 65536
#define N_PTS  (64 * 1001)          // 64064
#define BATCH  512

// ---------------------------------------------------------------------------
// Kernel 1: scatter touched cells. Benign race: all writers store 1.
// Mirrors: fx = x*256; rx = fx-floor(fx); in_box = rx,ry in [0.25,0.75];
//          flat = clip(ix)*N_ROW + clip(iy); touched[flat] max= in_box
// ---------------------------------------------------------------------------
__global__ void scatter_touch(const float* __restrict__ ax,
                              const float* __restrict__ ay,
                              int* __restrict__ touched) {
    int p = blockIdx.x * blockDim.x + threadIdx.x;
    if (p >= N_PTS) return;
    float fx = ax[p] * (float)N_COL;
    float fy = ay[p] * (float)N_ROW;
    float cx = floorf(fx);
    float cy = floorf(fy);
    float rx = fx - cx;
    float ry = fy - cy;
    bool in_box = (rx >= 0.25f) && (rx <= 0.75f) && (ry >= 0.25f) && (ry <= 0.75f);
    if (in_box) {
        int ix = min(max((int)cx, 0), N_COL - 1);
        int iy = min(max((int)cy, 0), N_ROW - 1);
        touched[ix * N_ROW + iy] = 1;   // plain store; kernel boundary syncs
    }
}

// ---------------------------------------------------------------------------
// Kernel 2: build rotated mask + exact integer sum of mask.
// rot90 CCW on square (256,256): rot[i][j] = m[j][255-i]
// mask values are 0/1 so f32 summation is order-independent (exact).
// ---------------------------------------------------------------------------
__global__ void build_mask(const int* __restrict__ touched,
                           float* __restrict__ mask_rot,
                           int* __restrict__ sum_out) {
    int k = blockIdx.x * blockDim.x + threadIdx.x;   // 0..65535
    int i = k >> 8;
    int j = k & 255;
    int src = j * N_ROW + (N_ROW - 1 - i);
    int m = 1 - touched[src];
    mask_rot[k] = (float)m;
    // wave-level popcount reduce, one atomic per wave (Guideline 12)
    unsigned long long b = __ballot(m != 0);
    if ((threadIdx.x & 63) == 0) {
        atomicAdd(sum_out, (int)__popcll(b));
    }
}

// ---------------------------------------------------------------------------
// Kernel 3: out = in * mask_rot * scale, float4-vectorized, grid-stride.
// scale replicates reference arithmetic exactly:
//   rate = 1 - s/65536 ; scale = 1/(1-rate)
// ---------------------------------------------------------------------------
__global__ void apply_mask(const float* __restrict__ in,
                           const float* __restrict__ mask_rot,
                           const int* __restrict__ sum_ptr,
                           float* __restrict__ out) {
    const unsigned total4 = (unsigned)BATCH * (N_NEUR / 4);   // 8,388,608
    float s = (float)(*sum_ptr);
    float rate = 1.0f - s / (float)N_NEUR;
    float scale = 1.0f / (1.0f - rate);

    const float4* __restrict__ in4   = (const float4*)in;
    const float4* __restrict__ mask4 = (const float4*)mask_rot;
    float4* __restrict__ out4        = (float4*)out;

    unsigned stride = gridDim.x * blockDim.x;
    for (unsigned idx = blockIdx.x * blockDim.x + threadIdx.x;
         idx < total4; idx += stride) {
        unsigned mIdx = idx & (N_NEUR / 4 - 1);   // row length divides evenly
        float4 v = in4[idx];
        float4 m = mask4[mIdx];
        float4 r;
        r.x = v.x * m.x * scale;
        r.y = v.y * m.y * scale;
        r.z = v.z * m.z * scale;
        r.w = v.w * m.w * scale;
        out4[idx] = r;
    }
}

// ---------------------------------------------------------------------------
// ws layout (ints): [0, 65536) touched | [65536] sum | [65540, +65536) mask_rot
// (mask_rot offset 65540*4 = 262160 bytes, 16B-aligned for float4)
// ---------------------------------------------------------------------------
extern "C" void kernel_launch(void* const* d_in, const int* in_sizes, int n_in,
                              void* d_out, int out_size, void* d_ws, size_t ws_size,
                              hipStream_t stream) {
    const float* input = (const float*)d_in[0];
    const float* ax    = (const float*)d_in[1];
    const float* ay    = (const float*)d_in[2];
    float* out = (float*)d_out;

    int*   touched  = (int*)d_ws;
    int*   sum_out  = touched + N_NEUR;
    float* mask_rot = (float*)((char*)d_ws + (N_NEUR + 4) * sizeof(int));

    // zero touched + sum (ws is re-poisoned to 0xAA before every timed call)
    hipMemsetAsync(touched, 0, (N_NEUR + 1) * sizeof(int), stream);

    scatter_touch<<<(N_PTS + 255) / 256, 256, 0, stream>>>(ax, ay, touched);
    build_mask<<<N_NEUR / 256, 256, 0, stream>>>(touched, mask_rot, sum_out);
    apply_mask<<<2048, 256, 0, stream>>>(input, mask_rot, sum_out, out);
}

// Round 6
// 240.046 us; speedup vs baseline: 1.0572x; 1.0572x over previous
//
#include <hip/hip_runtime.h>

#define N_COL 256
#define N_ROW 256
#define N_NEUR (N_COL * N_ROW)      // 65536
#define N_PTS  (64 * 1001)          // 64064
#define BATCH  512

// native clang vector type -> accepted by __builtin_nontemporal_{load,store}
typedef float f32x4 __attribute__((ext_vector_type(4)));

// ws layout: [0, 65536) float mask_rot | [65536] int count_touched
// (re-poisoned to 0xAA before every timed call -> init_mask rebuilds both)

// ---------------------------------------------------------------------------
// Kernel 1: mask = 1.0 everywhere, count = 0. (256 KB write, ~2 us)
// ---------------------------------------------------------------------------
__global__ void init_mask(float* __restrict__ mask, int* __restrict__ count) {
    int k = blockIdx.x * blockDim.x + threadIdx.x;
    mask[k] = 1.0f;
    if (k == 0) *count = 0;
}

// ---------------------------------------------------------------------------
// Kernel 2: scatter directly into the ROTATED mask.
// Reference: touched cell (ix,iy) -> m[ix][iy]=0; rot[i][j]=m[j][255-i]
//   => m[a][b] lands at rot[(255-b)][a], flat k = (255-iy)*256 + ix.
// atomicExch(1.0f->0) makes exactly ONE thread per distinct cell see the
// 1.0f bit pattern -> exact distinct-cell count without a second pass.
// sum(mask) = 65536 - count (exact integer, matches the reference's f32
// sum of 0/1 values bit-for-bit).
// ---------------------------------------------------------------------------
__global__ void scatter_touch(const float* __restrict__ ax,
                              const float* __restrict__ ay,
                              int* __restrict__ mask_bits,
                              int* __restrict__ count) {
    int p = blockIdx.x * blockDim.x + threadIdx.x;
    if (p >= N_PTS) return;
    float fx = ax[p] * (float)N_COL;
    float fy = ay[p] * (float)N_ROW;
    float cx = floorf(fx);
    float cy = floorf(fy);
    float rx = fx - cx;
    float ry = fy - cy;
    bool in_box = (rx >= 0.25f) && (rx <= 0.75f) && (ry >= 0.25f) && (ry <= 0.75f);
    if (in_box) {
        int ix = min(max((int)cx, 0), N_COL - 1);
        int iy = min(max((int)cy, 0), N_ROW - 1);
        int k = (N_ROW - 1 - iy) * N_COL + ix;   // rotated position
        int old = atomicExch(&mask_bits[k], 0);  // 0x3F800000 -> 0
        if (old != 0) atomicAdd(count, 1);       // first toucher only
    }
}

// ---------------------------------------------------------------------------
// Kernel 3: out = in * mask_rot * scale. float4 + nontemporal streaming.
// scale replicates reference arithmetic exactly (all ops exact for
// integer s <= 65536): rate = 1 - s/65536 ; scale = 1/(1-rate)
// ---------------------------------------------------------------------------
__global__ void apply_mask(const float* __restrict__ in,
                           const float* __restrict__ mask_rot,
                           const int* __restrict__ count_ptr,
                           float* __restrict__ out) {
    const unsigned total4 = (unsigned)BATCH * (N_NEUR / 4);   // 8,388,608
    float s = (float)(N_NEUR - *count_ptr);
    float rate = 1.0f - s / (float)N_NEUR;
    float scale = 1.0f / (1.0f - rate);

    const f32x4* __restrict__ in4   = (const f32x4*)in;
    const f32x4* __restrict__ mask4 = (const f32x4*)mask_rot;
    f32x4* __restrict__ out4        = (f32x4*)out;

    unsigned stride = gridDim.x * blockDim.x;
    for (unsigned idx = blockIdx.x * blockDim.x + threadIdx.x;
         idx < total4; idx += stride) {
        unsigned mIdx = idx & (N_NEUR / 4 - 1);   // row length divides grid
        f32x4 v = __builtin_nontemporal_load(&in4[idx]);   // read-once
        f32x4 m = mask4[mIdx];                             // L2-resident
        f32x4 r = v * m * scale;
        __builtin_nontemporal_store(r, &out4[idx]);        // write-once
    }
}

extern "C" void kernel_launch(void* const* d_in, const int* in_sizes, int n_in,
                              void* d_out, int out_size, void* d_ws, size_t ws_size,
                              hipStream_t stream) {
    const float* input = (const float*)d_in[0];
    const float* ax    = (const float*)d_in[1];
    const float* ay    = (const float*)d_in[2];
    float* out = (float*)d_out;

    float* mask_rot = (float*)d_ws;
    int*   count    = (int*)d_ws + N_NEUR;

    init_mask<<<N_NEUR / 256, 256, 0, stream>>>(mask_rot, count);
    scatter_touch<<<(N_PTS + 255) / 256, 256, 0, stream>>>(
        ax, ay, (int*)mask_rot, count);
    apply_mask<<<2048, 256, 0, stream>>>(input, mask_rot, count, out);
}